// Round 1
// baseline (929.772 us; speedup 1.0000x reference)
//
#include <hip/hip_runtime.h>

#define N_IN 512
#define HID 64
#define LOC 16
#define OUTC 40

__device__ inline float bf2f(unsigned short s) {
    union { unsigned int u; float f; } v; v.u = ((unsigned int)s) << 16; return v.f;
}
__device__ inline unsigned short f2bf(float f) {
    union { float f; unsigned int u; } v; v.f = f;
    unsigned int u = v.u;
    unsigned int r = (u + 0x7FFFu + ((u >> 16) & 1u)) >> 16;
    return (unsigned short)r;
}

// ---------------- edge-layout detection (int32 vs int64 storage) ----------
__global__ void k_detect(const int* __restrict__ EI, int* __restrict__ flag) {
    if (threadIdx.x == 0 && blockIdx.x == 0) {
        // if stored as int64 (values < 1e5), every high word is 0
        *flag = (EI[1] == 0 && EI[3] == 0 && EI[5] == 0 && EI[7] == 0) ? 1 : 0;
    }
}

// ---------------- degree / CSR build ----------------
__global__ __launch_bounds__(256) void k_init(int* __restrict__ deg, int* __restrict__ cursor, int N) {
    int i = blockIdx.x * 256 + threadIdx.x;
    if (i < N) { deg[i] = 1; cursor[i] = 0; }
}

__global__ __launch_bounds__(256) void k_count(const int* __restrict__ EI, const int* __restrict__ flag,
                                               int* __restrict__ deg, int E, int N) {
    int e = blockIdx.x * 256 + threadIdx.x;
    if (e >= E) return;
    int f = *flag;
    int c = f ? EI[2 * (E + e)] : EI[E + e];
    if ((unsigned)c < (unsigned)N) atomicAdd(&deg[c], 1);
}

__global__ __launch_bounds__(256) void k_scan_a(const int* __restrict__ deg, int* __restrict__ start,
                                                int* __restrict__ bsum, int N) {
    __shared__ int sd[256];
    int i = blockIdx.x * 256 + threadIdx.x;
    int v = (i < N) ? (deg[i] - 1) : 0;
    sd[threadIdx.x] = v;
    __syncthreads();
    for (int off = 1; off < 256; off <<= 1) {
        int t = 0;
        if (threadIdx.x >= (unsigned)off) t = sd[threadIdx.x - off];
        __syncthreads();
        sd[threadIdx.x] += t;
        __syncthreads();
    }
    if (i < N) start[i] = sd[threadIdx.x] - v;   // block-local exclusive
    if (threadIdx.x == 255) bsum[blockIdx.x] = sd[255];
}

__global__ __launch_bounds__(512) void k_scan_b(const int* __restrict__ bsum, int* __restrict__ bexc, int nb) {
    __shared__ int sd[512];
    int t = threadIdx.x;
    int v = (t < nb) ? bsum[t] : 0;
    sd[t] = v;
    __syncthreads();
    for (int off = 1; off < 512; off <<= 1) {
        int u = 0;
        if (t >= off) u = sd[t - off];
        __syncthreads();
        sd[t] += u;
        __syncthreads();
    }
    if (t < nb) bexc[t] = sd[t] - v;
    if (t == 511) bexc[nb] = sd[511];   // grand total = E
}

__global__ __launch_bounds__(256) void k_scan_c(const int* __restrict__ bexc, int* __restrict__ start,
                                                int N, int nb) {
    int i = blockIdx.x * 256 + threadIdx.x;
    if (i < N) start[i] += bexc[blockIdx.x];
    if (i == 0) start[N] = bexc[nb];
}

__global__ __launch_bounds__(256) void k_dinv(const int* __restrict__ deg, float* __restrict__ dinv, int N) {
    int i = blockIdx.x * 256 + threadIdx.x;
    if (i < N) dinv[i] = rsqrtf((float)deg[i]);
}

__global__ __launch_bounds__(256) void k_scatter(const int* __restrict__ EI, const int* __restrict__ flag,
                                                 const int* __restrict__ start, const float* __restrict__ dinv,
                                                 int* __restrict__ cursor, int2* __restrict__ edges,
                                                 int E, int N) {
    int e = blockIdx.x * 256 + threadIdx.x;
    if (e >= E) return;
    int f = *flag;
    int r = f ? EI[2 * e] : EI[e];
    int c = f ? EI[2 * (E + e)] : EI[E + e];
    if ((unsigned)r >= (unsigned)N || (unsigned)c >= (unsigned)N) return;
    int p = atomicAdd(&cursor[c], 1);
    int2 v; v.x = r; v.y = __float_as_int(dinv[r]);
    edges[start[c] + p] = v;
}

// ---------------- GEMM1: [N,512] x [512,64] -> bf16 [N,64] ----------------
__global__ __launch_bounds__(256) void k_gemm1(const float* __restrict__ X, const float* __restrict__ W,
                                               unsigned short* __restrict__ H, int N) {
    __shared__ float Xs[64][36];   // [row][k], stride 36 keeps 16B align + ok banks
    __shared__ float Ws[32][64];   // [k][col]
    int tid = threadIdx.x;
    int m0 = blockIdx.x * 64;
    int rg = tid >> 4, cg = tid & 15;
    int r0 = rg * 4, c0 = cg * 4;
    int lr = tid >> 3;             // 0..31
    int lk = (tid & 7) * 4;        // 0..28
    int wk = tid >> 4;             // 0..15
    int wc = (tid & 15) * 4;
    float acc[4][4] = {{0.f,0.f,0.f,0.f},{0.f,0.f,0.f,0.f},{0.f,0.f,0.f,0.f},{0.f,0.f,0.f,0.f}};
    for (int kc = 0; kc < 512; kc += 32) {
        float4 xv0 = make_float4(0.f,0.f,0.f,0.f), xv1 = xv0;
        int ra = m0 + lr, rb = ra + 32;
        if (ra < N) xv0 = *(const float4*)(X + (size_t)ra * 512 + kc + lk);
        if (rb < N) xv1 = *(const float4*)(X + (size_t)rb * 512 + kc + lk);
        float4 wv0 = *(const float4*)(W + (size_t)(kc + wk) * 64 + wc);
        float4 wv1 = *(const float4*)(W + (size_t)(kc + wk + 16) * 64 + wc);
        __syncthreads();
        *(float4*)&Xs[lr][lk]      = xv0;
        *(float4*)&Xs[lr + 32][lk] = xv1;
        *(float4*)&Ws[wk][wc]      = wv0;
        *(float4*)&Ws[wk + 16][wc] = wv1;
        __syncthreads();
#pragma unroll
        for (int k4 = 0; k4 < 8; ++k4) {
            float4 a0 = *(const float4*)&Xs[r0 + 0][k4 * 4];
            float4 a1 = *(const float4*)&Xs[r0 + 1][k4 * 4];
            float4 a2 = *(const float4*)&Xs[r0 + 2][k4 * 4];
            float4 a3 = *(const float4*)&Xs[r0 + 3][k4 * 4];
            float4 w0 = *(const float4*)&Ws[k4 * 4 + 0][c0];
            float4 w1 = *(const float4*)&Ws[k4 * 4 + 1][c0];
            float4 w2 = *(const float4*)&Ws[k4 * 4 + 2][c0];
            float4 w3 = *(const float4*)&Ws[k4 * 4 + 3][c0];
#define FMA_ROW(i, A) \
            acc[i][0] += A.x*w0.x + A.y*w1.x + A.z*w2.x + A.w*w3.x; \
            acc[i][1] += A.x*w0.y + A.y*w1.y + A.z*w2.y + A.w*w3.y; \
            acc[i][2] += A.x*w0.z + A.y*w1.z + A.z*w2.z + A.w*w3.z; \
            acc[i][3] += A.x*w0.w + A.y*w1.w + A.z*w2.w + A.w*w3.w;
            FMA_ROW(0, a0) FMA_ROW(1, a1) FMA_ROW(2, a2) FMA_ROW(3, a3)
#undef FMA_ROW
        }
    }
#pragma unroll
    for (int i = 0; i < 4; ++i) {
        int m = m0 + r0 + i;
        if (m < N) {
            ushort4 o;
            o.x = f2bf(acc[i][0]); o.y = f2bf(acc[i][1]);
            o.z = f2bf(acc[i][2]); o.w = f2bf(acc[i][3]);
            *(ushort4*)(H + (size_t)m * 64 + c0) = o;
        }
    }
}

// ---------------- agg layer 1: wave per node, lane = channel (64) ----------
__global__ __launch_bounds__(256) void k_agg1(const unsigned short* __restrict__ H, const int2* __restrict__ edges,
                                              const int* __restrict__ start, const float* __restrict__ dinv,
                                              const float* __restrict__ b1, unsigned short* __restrict__ X1, int N) {
    int wid = blockIdx.x * 4 + (threadIdx.x >> 6);
    int lane = threadIdx.x & 63;
    if (wid >= N) return;
    float dv = dinv[wid];
    int s = start[wid], e = start[wid + 1];
    float acc = bf2f(H[(size_t)wid * 64 + lane]) * dv;   // self term (x dv again later)
    int i = s;
    if (i < e && (i & 1)) {  // peel to 16B-align the int4 loads
        int2 ed = edges[i];
        acc += __int_as_float(ed.y) * bf2f(H[(size_t)ed.x * 64 + lane]);
        ++i;
    }
    for (; i + 1 < e; i += 2) {
        int4 ed = *(const int4*)(edges + i);
        float h0 = bf2f(H[(size_t)ed.x * 64 + lane]);
        float h1 = bf2f(H[(size_t)ed.z * 64 + lane]);
        acc += __int_as_float(ed.y) * h0 + __int_as_float(ed.w) * h1;
    }
    if (i < e) {
        int2 ed = edges[i];
        acc += __int_as_float(ed.y) * bf2f(H[(size_t)ed.x * 64 + lane]);
    }
    float r = acc * dv + b1[lane];
    X1[(size_t)wid * 64 + lane] = f2bf(r > 0.f ? r : 0.f);
}

// ---------------- GEMM2: bf16 [N,64] x f32 [64,16] -> bf16 [N,16] ----------
__global__ __launch_bounds__(256) void k_gemm2(const unsigned short* __restrict__ X1, const float* __restrict__ W2,
                                               unsigned short* __restrict__ H2, int N) {
    __shared__ float Ws[1024];     // [k][c] 64x16
    __shared__ float Xs[64][68];   // [r][k]
    int tid = threadIdx.x;
    for (int i = tid; i < 1024; i += 256) Ws[i] = W2[i];
    int m0 = blockIdx.x * 64;
#pragma unroll
    for (int j = 0; j < 4; ++j) {
        int f = (j * 256 + tid) * 4;   // element idx 0..4095
        int r = f >> 6, k = f & 63;
        uint2 v = make_uint2(0u, 0u);
        if (m0 + r < N) v = *(const uint2*)(X1 + (size_t)(m0 + r) * 64 + k);
        Xs[r][k + 0] = bf2f((unsigned short)(v.x & 0xffffu));
        Xs[r][k + 1] = bf2f((unsigned short)(v.x >> 16));
        Xs[r][k + 2] = bf2f((unsigned short)(v.y & 0xffffu));
        Xs[r][k + 3] = bf2f((unsigned short)(v.y >> 16));
    }
    __syncthreads();
    int r = tid >> 2, cq = tid & 3;
    float acc0 = 0.f, acc1 = 0.f, acc2 = 0.f, acc3 = 0.f;
#pragma unroll 8
    for (int k = 0; k < 64; ++k) {
        float xv = Xs[r][k];
        const float* wp = &Ws[k * 16 + cq * 4];
        acc0 += xv * wp[0]; acc1 += xv * wp[1]; acc2 += xv * wp[2]; acc3 += xv * wp[3];
    }
    int m = m0 + r;
    if (m < N) {
        ushort4 o; o.x = f2bf(acc0); o.y = f2bf(acc1); o.z = f2bf(acc2); o.w = f2bf(acc3);
        *(ushort4*)(H2 + (size_t)m * 16 + cq * 4) = o;
    }
}

// ---------------- agg layer 2: wave per node, 4 edges x 16 channels --------
__global__ __launch_bounds__(256) void k_agg2(const unsigned short* __restrict__ H2, const int2* __restrict__ edges,
                                              const int* __restrict__ start, const float* __restrict__ dinv,
                                              const float* __restrict__ b2, float* __restrict__ X2, int N) {
    int wid = blockIdx.x * 4 + (threadIdx.x >> 6);
    int lane = threadIdx.x & 63;
    if (wid >= N) return;
    int eo = lane >> 4, c = lane & 15;
    float dv = dinv[wid];
    int s = start[wid], e = start[wid + 1];
    float acc = 0.f;
    for (int i = s; i < e; i += 4) {
        int j = i + eo;
        int src = 0; float f = 0.f;
        if (j < e) { int2 ed = edges[j]; src = ed.x; f = __int_as_float(ed.y); }
        acc += f * bf2f(H2[(size_t)src * 16 + c]);
    }
    acc += __shfl_xor(acc, 16, 64);
    acc += __shfl_xor(acc, 32, 64);
    float hs = bf2f(H2[(size_t)wid * 16 + c]);
    float r = (acc + hs * dv) * dv + b2[c];
    if (lane < 16) X2[(size_t)wid * 16 + c] = r;
}

// ---------------- attention head + final linear ----------------
__global__ __launch_bounds__(256) void k_head(const float* __restrict__ X2, const float* __restrict__ G,
                                              const float* __restrict__ AW1, const float* __restrict__ AB1,
                                              const float* __restrict__ AW2, const float* __restrict__ LW,
                                              const float* __restrict__ LB, float* __restrict__ OUT, int N) {
    __shared__ float s_aw1[256], s_ab1[16], s_aw2[16], s_lw[640], s_lb[40];
    int tid = threadIdx.x;
    s_aw1[tid] = AW1[tid];
    if (tid < 16) { s_ab1[tid] = AB1[tid]; s_aw2[tid] = AW2[tid]; }
    for (int i = tid; i < 640; i += 256) s_lw[i] = LW[i];
    if (tid < 40) s_lb[tid] = LB[tid];
    __syncthreads();
    int node = blockIdx.x * 256 + tid;
    if (node >= N) return;
    float x[16], g[16];
    const float4* xp = (const float4*)(X2 + (size_t)node * 16);
    const float4* gp = (const float4*)(G + (size_t)node * 16);
#pragma unroll
    for (int q = 0; q < 4; ++q) {
        float4 v = xp[q]; x[q*4] = v.x; x[q*4+1] = v.y; x[q*4+2] = v.z; x[q*4+3] = v.w;
        float4 u = gp[q]; g[q*4] = u.x; g[q*4+1] = u.y; g[q*4+2] = u.z; g[q*4+3] = u.w;
    }
    float wx = 0.f, wg = 0.f;
#pragma unroll
    for (int j = 0; j < 16; ++j) {
        float tx = s_ab1[j], tg = s_ab1[j];
#pragma unroll
        for (int c = 0; c < 16; ++c) { tx += x[c] * s_aw1[c*16 + j]; tg += g[c] * s_aw1[c*16 + j]; }
        wx += tanhf(tx) * s_aw2[j];
        wg += tanhf(tg) * s_aw2[j];
    }
    float m = fmaxf(wx, wg);
    float ex = expf(wx - m), eg = expf(wg - m);
    float inv = 1.f / (ex + eg);
    float bx = ex * inv, bg = eg * inv;
    float emb[16];
#pragma unroll
    for (int c = 0; c < 16; ++c) emb[c] = bx * x[c] + bg * g[c];
    float* op = OUT + (size_t)node * 40;
    for (int o = 0; o < 40; ++o) {
        float a = s_lb[o];
#pragma unroll
        for (int c = 0; c < 16; ++c) a += emb[c] * s_lw[c*40 + o];
        op[o] = a;
    }
}

extern "C" void kernel_launch(void* const* d_in, const int* in_sizes, int n_in,
                              void* d_out, int out_size, void* d_ws, size_t ws_size,
                              hipStream_t stream) {
    const float* X   = (const float*)d_in[0];
    const int*   EI  = (const int*)d_in[1];
    const float* G   = (const float*)d_in[2];
    const float* W1  = (const float*)d_in[3];
    const float* B1  = (const float*)d_in[4];
    const float* W2  = (const float*)d_in[5];
    const float* B2  = (const float*)d_in[6];
    const float* AW1 = (const float*)d_in[7];
    const float* AB1 = (const float*)d_in[8];
    const float* AW2 = (const float*)d_in[9];
    const float* LW  = (const float*)d_in[10];
    const float* LB  = (const float*)d_in[11];
    float* OUT = (float*)d_out;

    const int N = in_sizes[0] / N_IN;     // 100000
    const int E = in_sizes[1] / 2;        // 3200000
    const int NB = (N + 255) / 256;       // 391

    char* w = (char*)d_ws;
    size_t off = 0;
    auto take = [&](size_t bytes) -> void* {
        void* p = (void*)(w + off);
        off = (off + bytes + 255) & ~(size_t)255;
        return p;
    };
    int*   deg    = (int*)take((size_t)N * 4);
    int*   cursor = (int*)take((size_t)N * 4);
    int*   startp = (int*)take((size_t)(N + 1) * 4);
    int*   bsum   = (int*)take((size_t)NB * 4);
    int*   bexc   = (int*)take((size_t)(NB + 1) * 4);
    int*   flag   = (int*)take(16);
    float* dinvp  = (float*)take((size_t)N * 4);
    int2*  edges  = (int2*)take((size_t)E * 8);
    unsigned short* h1 = (unsigned short*)take((size_t)N * 64 * 2);
    unsigned short* x1 = (unsigned short*)take((size_t)N * 64 * 2);
    unsigned short* h2 = (unsigned short*)take((size_t)N * 16 * 2);
    float* x2 = (float*)take((size_t)N * 16 * 4);
    (void)ws_size; (void)n_in; (void)out_size; (void)B2;

    const int EB = (E + 255) / 256;

    k_detect<<<1, 64, 0, stream>>>(EI, flag);
    k_init<<<NB, 256, 0, stream>>>(deg, cursor, N);
    k_count<<<EB, 256, 0, stream>>>(EI, flag, deg, E, N);
    k_scan_a<<<NB, 256, 0, stream>>>(deg, startp, bsum, N);
    k_scan_b<<<1, 512, 0, stream>>>(bsum, bexc, NB);
    k_scan_c<<<NB, 256, 0, stream>>>(bexc, startp, N, NB);
    k_dinv<<<NB, 256, 0, stream>>>(deg, dinvp, N);
    k_scatter<<<EB, 256, 0, stream>>>(EI, flag, startp, dinvp, cursor, edges, E, N);
    k_gemm1<<<(N + 63) / 64, 256, 0, stream>>>(X, W1, h1, N);
    k_agg1<<<(N + 3) / 4, 256, 0, stream>>>(h1, edges, startp, dinvp, B1, x1, N);
    k_gemm2<<<(N + 63) / 64, 256, 0, stream>>>(x1, W2, h2, N);
    k_agg2<<<(N + 3) / 4, 256, 0, stream>>>(h2, edges, startp, dinvp, B2, x2, N);
    k_head<<<NB, 256, 0, stream>>>(x2, G, AW1, AB1, AW2, LW, LB, OUT, N);
}

// Round 2
// 893.632 us; speedup vs baseline: 1.0404x; 1.0404x over previous
//
#include <hip/hip_runtime.h>

#define N_IN 512
#define HID 64

typedef __attribute__((ext_vector_type(4))) float f32x4;
typedef __attribute__((ext_vector_type(8))) short bf16x8;

__device__ inline float bf2f(unsigned short s) {
    union { unsigned int u; float f; } v; v.u = ((unsigned int)s) << 16; return v.f;
}
__device__ inline unsigned short f2bf(float f) {
    union { float f; unsigned int u; } v; v.f = f;
    unsigned int u = v.u;
    return (unsigned short)((u + 0x7FFFu + ((u >> 16) & 1u)) >> 16);
}

// ---------------- init: deg=1, detect int64-vs-int32 edge storage ----------
__global__ __launch_bounds__(256) void k_init(const int* __restrict__ EI, int* __restrict__ flag,
                                              int* __restrict__ deg, int N) {
    int i = blockIdx.x * 256 + threadIdx.x;
    if (i < N) deg[i] = 1;
    if (i == 0) *flag = (EI[1] == 0 && EI[3] == 0 && EI[5] == 0 && EI[7] == 0) ? 1 : 0;
}

__global__ __launch_bounds__(256) void k_count(const int* __restrict__ EI, const int* __restrict__ flag,
                                               int* __restrict__ deg, int E, int N) {
    int e = blockIdx.x * 256 + threadIdx.x;
    if (e >= E) return;
    int c = (*flag) ? ((const int2*)EI)[E + e].x : EI[E + e];
    if ((unsigned)c < (unsigned)N) atomicAdd(&deg[c], 1);
}

__global__ __launch_bounds__(256) void k_scan_a(const int* __restrict__ deg, int* __restrict__ start,
                                                int* __restrict__ bsum, int N) {
    __shared__ int sd[256];
    int i = blockIdx.x * 256 + threadIdx.x;
    int v = (i < N) ? (deg[i] - 1) : 0;
    sd[threadIdx.x] = v;
    __syncthreads();
    for (int off = 1; off < 256; off <<= 1) {
        int t = 0;
        if (threadIdx.x >= (unsigned)off) t = sd[threadIdx.x - off];
        __syncthreads();
        sd[threadIdx.x] += t;
        __syncthreads();
    }
    if (i < N) start[i] = sd[threadIdx.x] - v;
    if (threadIdx.x == 255) bsum[blockIdx.x] = sd[255];
}

__global__ __launch_bounds__(512) void k_scan_b(const int* __restrict__ bsum, int* __restrict__ bexc, int nb) {
    __shared__ int sd[512];
    int t = threadIdx.x;
    int v = (t < nb) ? bsum[t] : 0;
    sd[t] = v;
    __syncthreads();
    for (int off = 1; off < 512; off <<= 1) {
        int u = 0;
        if (t >= off) u = sd[t - off];
        __syncthreads();
        sd[t] += u;
        __syncthreads();
    }
    if (t < nb) bexc[t] = sd[t] - v;
    if (t == 511) bexc[nb] = sd[511];
}

// scan fixup + dinv + cursor init (cursor = start copy; scatter atomics give absolute slots)
__global__ __launch_bounds__(256) void k_scan_cd(const int* __restrict__ bexc, const int* __restrict__ deg,
                                                 int* __restrict__ start, int* __restrict__ cursor,
                                                 float* __restrict__ dinv, int N, int nb) {
    int i = blockIdx.x * 256 + threadIdx.x;
    if (i < N) {
        int v = start[i] + bexc[blockIdx.x];
        start[i] = v;
        cursor[i] = v;
        dinv[i] = rsqrtf((float)deg[i]);
    }
    if (i == 0) start[N] = bexc[nb];
}

// W1 [512][64] fp32 -> Wt [64][512] bf16
__global__ __launch_bounds__(256) void k_wt(const float* __restrict__ W, unsigned short* __restrict__ Wt) {
    int i = blockIdx.x * 256 + threadIdx.x;   // 0..32767
    int k = i >> 6, n = i & 63;
    Wt[n * 512 + k] = f2bf(W[i]);
}

__global__ __launch_bounds__(256) void k_scatter(const int* __restrict__ EI, const int* __restrict__ flag,
                                                 int* __restrict__ cursor, int* __restrict__ edges,
                                                 int E, int N) {
    int e = blockIdx.x * 256 + threadIdx.x;
    if (e >= E) return;
    int r, c;
    if (*flag) { const int2* E2 = (const int2*)EI; r = E2[e].x; c = E2[E + e].x; }
    else       { r = EI[e]; c = EI[E + e]; }
    if ((unsigned)r >= (unsigned)N || (unsigned)c >= (unsigned)N) return;
    int p = atomicAdd(&cursor[c], 1);
    edges[p] = r;
}

// ---------------- GEMM1 (MFMA, no LDS): H[m] = dinv[m] * (X[m]·W1), bf16 out
// wave computes 32 rows x 64 cols via 16x16x32 bf16 MFMA; A from X (fp32->bf16 inline), B from Wt.
__global__ __launch_bounds__(256) void k_gemm1(const float* __restrict__ X, const unsigned short* __restrict__ Wt,
                                               const float* __restrict__ dinv, unsigned short* __restrict__ H, int N) {
    int tid = threadIdx.x;
    int w = tid >> 6, lane = tid & 63;
    int m_l = lane & 15, q = lane >> 4;
    int m0 = blockIdx.x * 128 + w * 32;
    int rA0 = m0 + m_l, rA1 = m0 + 16 + m_l;
    int rc0 = rA0 < N ? rA0 : N - 1;
    int rc1 = rA1 < N ? rA1 : N - 1;
    const float* baseA0 = X + (size_t)rc0 * 512 + q * 8;
    const float* baseA1 = X + (size_t)rc1 * 512 + q * 8;
    const unsigned short* baseB = Wt + (size_t)m_l * 512 + q * 8;   // + t*16*512

    f32x4 acc[2][4] = {};
#pragma unroll 4
    for (int c = 0; c < 16; ++c) {
        int ko = c * 32;
        float4 x0a = *(const float4*)(baseA0 + ko);
        float4 x0b = *(const float4*)(baseA0 + ko + 4);
        float4 x1a = *(const float4*)(baseA1 + ko);
        float4 x1b = *(const float4*)(baseA1 + ko + 4);
        bf16x8 a0, a1;
        a0[0] = (short)f2bf(x0a.x); a0[1] = (short)f2bf(x0a.y); a0[2] = (short)f2bf(x0a.z); a0[3] = (short)f2bf(x0a.w);
        a0[4] = (short)f2bf(x0b.x); a0[5] = (short)f2bf(x0b.y); a0[6] = (short)f2bf(x0b.z); a0[7] = (short)f2bf(x0b.w);
        a1[0] = (short)f2bf(x1a.x); a1[1] = (short)f2bf(x1a.y); a1[2] = (short)f2bf(x1a.z); a1[3] = (short)f2bf(x1a.w);
        a1[4] = (short)f2bf(x1b.x); a1[5] = (short)f2bf(x1b.y); a1[6] = (short)f2bf(x1b.z); a1[7] = (short)f2bf(x1b.w);
#pragma unroll
        for (int t = 0; t < 4; ++t) {
            bf16x8 b = *(const bf16x8*)(baseB + (size_t)t * 16 * 512 + ko);
            acc[0][t] = __builtin_amdgcn_mfma_f32_16x16x32_bf16(a0, b, acc[0][t], 0, 0, 0);
            acc[1][t] = __builtin_amdgcn_mfma_f32_16x16x32_bf16(a1, b, acc[1][t], 0, 0, 0);
        }
    }
#pragma unroll
    for (int h = 0; h < 2; ++h) {
#pragma unroll
        for (int rg = 0; rg < 4; ++rg) {
            int row = m0 + h * 16 + q * 4 + rg;
            if (row < N) {
                float dv = dinv[row];
#pragma unroll
                for (int t = 0; t < 4; ++t)
                    H[(size_t)row * 64 + t * 16 + m_l] = f2bf(acc[h][t][rg] * dv);
            }
        }
    }
}

// ---------------- agg1: wave/node, lane=channel, 8 gathers in flight -------
__global__ __launch_bounds__(256) void k_agg1(const unsigned short* __restrict__ H, const int* __restrict__ edges,
                                              const int* __restrict__ start, const float* __restrict__ dinv,
                                              const float* __restrict__ b1, unsigned short* __restrict__ X1, int N) {
    int wid = blockIdx.x * 4 + (threadIdx.x >> 6);
    int lane = threadIdx.x & 63;
    if (wid >= N) return;
    float dv = dinv[wid];
    int s = start[wid], e = start[wid + 1];
    float acc = bf2f(H[(size_t)wid * 64 + lane]);   // self (already dinv-scaled)
    int i = s;
    while (i < e && (i & 3)) { acc += bf2f(H[(size_t)edges[i] * 64 + lane]); ++i; }
    for (; i + 8 <= e; i += 8) {
        int4 e0 = *(const int4*)(edges + i);
        int4 e1 = *(const int4*)(edges + i + 4);
        float h0 = bf2f(H[(size_t)e0.x * 64 + lane]);
        float h1 = bf2f(H[(size_t)e0.y * 64 + lane]);
        float h2 = bf2f(H[(size_t)e0.z * 64 + lane]);
        float h3 = bf2f(H[(size_t)e0.w * 64 + lane]);
        float h4 = bf2f(H[(size_t)e1.x * 64 + lane]);
        float h5 = bf2f(H[(size_t)e1.y * 64 + lane]);
        float h6 = bf2f(H[(size_t)e1.z * 64 + lane]);
        float h7 = bf2f(H[(size_t)e1.w * 64 + lane]);
        acc += ((h0 + h1) + (h2 + h3)) + ((h4 + h5) + (h6 + h7));
    }
    if (i + 4 <= e) {
        int4 e0 = *(const int4*)(edges + i);
        acc += bf2f(H[(size_t)e0.x * 64 + lane]) + bf2f(H[(size_t)e0.y * 64 + lane])
             + bf2f(H[(size_t)e0.z * 64 + lane]) + bf2f(H[(size_t)e0.w * 64 + lane]);
        i += 4;
    }
    for (; i < e; ++i) acc += bf2f(H[(size_t)edges[i] * 64 + lane]);
    float r = acc * dv + b1[lane];
    X1[(size_t)wid * 64 + lane] = f2bf(fmaxf(r, 0.f));
}

// ---------------- GEMM2: bf16 [N,64] x f32 [64,16] -> dinv-scaled bf16 [N,16]
__global__ __launch_bounds__(256) void k_gemm2(const unsigned short* __restrict__ X1, const float* __restrict__ W2,
                                               const float* __restrict__ dinv, unsigned short* __restrict__ H2, int N) {
    __shared__ float Ws[1024];
    __shared__ float Xs[64][68];
    int tid = threadIdx.x;
    for (int i = tid; i < 1024; i += 256) Ws[i] = W2[i];
    int m0 = blockIdx.x * 64;
#pragma unroll
    for (int j = 0; j < 4; ++j) {
        int f = (j * 256 + tid) * 4;
        int r = f >> 6, k = f & 63;
        uint2 v = make_uint2(0u, 0u);
        if (m0 + r < N) v = *(const uint2*)(X1 + (size_t)(m0 + r) * 64 + k);
        Xs[r][k + 0] = bf2f((unsigned short)(v.x & 0xffffu));
        Xs[r][k + 1] = bf2f((unsigned short)(v.x >> 16));
        Xs[r][k + 2] = bf2f((unsigned short)(v.y & 0xffffu));
        Xs[r][k + 3] = bf2f((unsigned short)(v.y >> 16));
    }
    __syncthreads();
    int r = tid >> 2, cq = tid & 3;
    float acc0 = 0.f, acc1 = 0.f, acc2 = 0.f, acc3 = 0.f;
#pragma unroll 8
    for (int k = 0; k < 64; ++k) {
        float xv = Xs[r][k];
        const float* wp = &Ws[k * 16 + cq * 4];
        acc0 += xv * wp[0]; acc1 += xv * wp[1]; acc2 += xv * wp[2]; acc3 += xv * wp[3];
    }
    int m = m0 + r;
    if (m < N) {
        float dv = dinv[m];
        ushort4 o; o.x = f2bf(acc0 * dv); o.y = f2bf(acc1 * dv); o.z = f2bf(acc2 * dv); o.w = f2bf(acc3 * dv);
        *(ushort4*)(H2 + (size_t)m * 16 + cq * 4) = o;
    }
}

// ---------------- agg2: wave/node, 4 edge-slots x 16 ch, 8 edges in flight --
__global__ __launch_bounds__(256) void k_agg2(const unsigned short* __restrict__ H2, const int* __restrict__ edges,
                                              const int* __restrict__ start, const float* __restrict__ dinv,
                                              const float* __restrict__ b2, float* __restrict__ X2, int N) {
    int wid = blockIdx.x * 4 + (threadIdx.x >> 6);
    int lane = threadIdx.x & 63;
    if (wid >= N) return;
    int eo = lane >> 4, c = lane & 15;
    float dv = dinv[wid];
    int s = start[wid], e = start[wid + 1];
    float acc = 0.f;
    int i = s;
    for (; i + 8 <= e; i += 8) {
        int s0 = edges[i + eo], s1 = edges[i + eo + 4];
        acc += bf2f(H2[(size_t)s0 * 16 + c]) + bf2f(H2[(size_t)s1 * 16 + c]);
    }
    for (; i < e; i += 4) {
        int j = i + eo;
        if (j < e) acc += bf2f(H2[(size_t)edges[j] * 16 + c]);
    }
    acc += __shfl_xor(acc, 16, 64);
    acc += __shfl_xor(acc, 32, 64);
    float hs = bf2f(H2[(size_t)wid * 16 + c]);   // already dinv-scaled
    float r = (acc + hs) * dv + b2[c];
    if (lane < 16) X2[(size_t)wid * 16 + c] = r;
}

// ---------------- attention head + final linear ----------------
__global__ __launch_bounds__(256) void k_head(const float* __restrict__ X2, const float* __restrict__ G,
                                              const float* __restrict__ AW1, const float* __restrict__ AB1,
                                              const float* __restrict__ AW2, const float* __restrict__ LW,
                                              const float* __restrict__ LB, float* __restrict__ OUT, int N) {
    __shared__ float s_aw1[256], s_ab1[16], s_aw2[16], s_lw[640], s_lb[40];
    int tid = threadIdx.x;
    s_aw1[tid] = AW1[tid];
    if (tid < 16) { s_ab1[tid] = AB1[tid]; s_aw2[tid] = AW2[tid]; }
    for (int i = tid; i < 640; i += 256) s_lw[i] = LW[i];
    if (tid < 40) s_lb[tid] = LB[tid];
    __syncthreads();
    int node = blockIdx.x * 256 + tid;
    if (node >= N) return;
    float x[16], g[16];
    const float4* xp = (const float4*)(X2 + (size_t)node * 16);
    const float4* gp = (const float4*)(G + (size_t)node * 16);
#pragma unroll
    for (int q = 0; q < 4; ++q) {
        float4 v = xp[q]; x[q*4] = v.x; x[q*4+1] = v.y; x[q*4+2] = v.z; x[q*4+3] = v.w;
        float4 u = gp[q]; g[q*4] = u.x; g[q*4+1] = u.y; g[q*4+2] = u.z; g[q*4+3] = u.w;
    }
    float wx = 0.f, wg = 0.f;
#pragma unroll
    for (int j = 0; j < 16; ++j) {
        float tx = s_ab1[j], tg = s_ab1[j];
#pragma unroll
        for (int c = 0; c < 16; ++c) { tx += x[c] * s_aw1[c*16 + j]; tg += g[c] * s_aw1[c*16 + j]; }
        wx += tanhf(tx) * s_aw2[j];
        wg += tanhf(tg) * s_aw2[j];
    }
    float m = fmaxf(wx, wg);
    float ex = expf(wx - m), eg = expf(wg - m);
    float inv = 1.f / (ex + eg);
    float bx = ex * inv, bg = eg * inv;
    float emb[16];
#pragma unroll
    for (int c = 0; c < 16; ++c) emb[c] = bx * x[c] + bg * g[c];
    float* op = OUT + (size_t)node * 40;
    for (int o = 0; o < 40; ++o) {
        float a = s_lb[o];
#pragma unroll
        for (int c = 0; c < 16; ++c) a += emb[c] * s_lw[c*40 + o];
        op[o] = a;
    }
}

extern "C" void kernel_launch(void* const* d_in, const int* in_sizes, int n_in,
                              void* d_out, int out_size, void* d_ws, size_t ws_size,
                              hipStream_t stream) {
    const float* X   = (const float*)d_in[0];
    const int*   EI  = (const int*)d_in[1];
    const float* G   = (const float*)d_in[2];
    const float* W1  = (const float*)d_in[3];
    const float* B1  = (const float*)d_in[4];
    const float* W2  = (const float*)d_in[5];
    const float* B2  = (const float*)d_in[6];
    const float* AW1 = (const float*)d_in[7];
    const float* AB1 = (const float*)d_in[8];
    const float* AW2 = (const float*)d_in[9];
    const float* LW  = (const float*)d_in[10];
    const float* LB  = (const float*)d_in[11];
    float* OUT = (float*)d_out;

    const int N = in_sizes[0] / N_IN;
    const int E = in_sizes[1] / 2;
    const int NB = (N + 255) / 256;
    const int EB = (E + 255) / 256;

    char* w = (char*)d_ws;
    size_t off = 0;
    auto take = [&](size_t bytes) -> void* {
        void* p = (void*)(w + off);
        off = (off + bytes + 255) & ~(size_t)255;
        return p;
    };
    int*   deg    = (int*)take((size_t)N * 4);
    int*   cursor = (int*)take((size_t)N * 4);
    int*   startp = (int*)take((size_t)(N + 1) * 4);
    int*   bsum   = (int*)take((size_t)NB * 4);
    int*   bexc   = (int*)take((size_t)(NB + 1) * 4);
    int*   flag   = (int*)take(16);
    float* dinvp  = (float*)take((size_t)N * 4);
    int*   edges  = (int*)take((size_t)E * 4);
    unsigned short* wt = (unsigned short*)take((size_t)N_IN * HID * 2);
    unsigned short* h1 = (unsigned short*)take((size_t)N * 64 * 2);
    unsigned short* x1 = (unsigned short*)take((size_t)N * 64 * 2);
    unsigned short* h2 = (unsigned short*)take((size_t)N * 16 * 2);
    float* x2 = (float*)take((size_t)N * 16 * 4);
    (void)ws_size; (void)n_in; (void)out_size;

    k_init   <<<NB, 256, 0, stream>>>(EI, flag, deg, N);
    k_count  <<<EB, 256, 0, stream>>>(EI, flag, deg, E, N);
    k_scan_a <<<NB, 256, 0, stream>>>(deg, startp, bsum, N);
    k_scan_b <<<1, 512, 0, stream>>>(bsum, bexc, NB);
    k_scan_cd<<<NB, 256, 0, stream>>>(bexc, deg, startp, cursor, dinvp, N, NB);
    k_wt     <<<(N_IN * HID + 255) / 256, 256, 0, stream>>>(W1, wt);
    k_scatter<<<EB, 256, 0, stream>>>(EI, flag, cursor, edges, E, N);
    k_gemm1  <<<(N + 127) / 128, 256, 0, stream>>>(X, wt, dinvp, h1, N);
    k_agg1   <<<(N + 3) / 4, 256, 0, stream>>>(h1, edges, startp, dinvp, B1, x1, N);
    k_gemm2  <<<(N + 63) / 64, 256, 0, stream>>>(x1, W2, dinvp, h2, N);
    k_agg2   <<<(N + 3) / 4, 256, 0, stream>>>(h2, edges, startp, dinvp, B2, x2, N);
    k_head   <<<NB, 256, 0, stream>>>(x2, G, AW1, AB1, AW2, LW, LB, OUT, N);
}

// Round 3
// 597.732 us; speedup vs baseline: 1.5555x; 1.4950x over previous
//
#include <hip/hip_runtime.h>

#define N_IN 512
#define HID 64
#define NBLK 256   // edge-chunk blocks for hist/partition passes

typedef __attribute__((ext_vector_type(4))) float f32x4;
typedef __attribute__((ext_vector_type(8))) short bf16x8;

__device__ inline float bf2f(unsigned short s) {
    union { unsigned int u; float f; } v; v.u = ((unsigned int)s) << 16; return v.f;
}
__device__ inline unsigned short f2bf(float f) {
    union { float f; unsigned int u; } v; v.f = f;
    unsigned int u = v.u;
    return (unsigned short)((u + 0x7FFFu + ((u >> 16) & 1u)) >> 16);
}

// ---------------- detect int64-vs-int32 edge storage ----------
__global__ void k_detect(const int* __restrict__ EI, int* __restrict__ flag) {
    if (threadIdx.x == 0 && blockIdx.x == 0)
        *flag = (EI[1] == 0 && EI[3] == 0 && EI[5] == 0 && EI[7] == 0) ? 1 : 0;
}

// ---------------- pass A: per-(bucket, block) histogram (LDS atomics only) --
__global__ __launch_bounds__(256) void k_histA(const int* __restrict__ EI, const int* __restrict__ flag,
                                               int* __restrict__ hist, int E, int N, int K) {
    extern __shared__ int hs[];
    for (int k = threadIdx.x; k < K; k += 256) hs[k] = 0;
    __syncthreads();
    int chunk = (E + NBLK - 1) / NBLK;
    int s = blockIdx.x * chunk, e = min(E, s + chunk);
    bool f = (*flag) != 0;
    for (int i = s + threadIdx.x; i < e; i += 256) {
        int c = f ? ((const int2*)EI)[E + i].x : EI[E + i];
        if ((unsigned)c < (unsigned)N) atomicAdd(&hs[c >> 8], 1);
    }
    __syncthreads();
    for (int k = threadIdx.x; k < K; k += 256) hist[k * NBLK + blockIdx.x] = hs[k];
}

// ---------------- generic 3-phase exclusive scan ----------------
__global__ __launch_bounds__(256) void k_scan_a2(const int* __restrict__ in, int* __restrict__ out,
                                                 int* __restrict__ bsum, int n) {
    __shared__ int sd[256];
    int i = blockIdx.x * 256 + threadIdx.x;
    int v = (i < n) ? in[i] : 0;
    sd[threadIdx.x] = v;
    __syncthreads();
    for (int off = 1; off < 256; off <<= 1) {
        int t = 0;
        if (threadIdx.x >= (unsigned)off) t = sd[threadIdx.x - off];
        __syncthreads();
        sd[threadIdx.x] += t;
        __syncthreads();
    }
    if (i < n) out[i] = sd[threadIdx.x] - v;
    if (threadIdx.x == 255) bsum[blockIdx.x] = sd[255];
}

__global__ __launch_bounds__(512) void k_scan_b(const int* __restrict__ bsum, int* __restrict__ bexc, int nb) {
    __shared__ int sd[512];
    int t = threadIdx.x;
    int v = (t < nb) ? bsum[t] : 0;
    sd[t] = v;
    __syncthreads();
    for (int off = 1; off < 512; off <<= 1) {
        int u = 0;
        if (t >= off) u = sd[t - off];
        __syncthreads();
        sd[t] += u;
        __syncthreads();
    }
    if (t < nb) bexc[t] = sd[t] - v;
    if (t == 511) bexc[nb] = sd[511];
}

__global__ __launch_bounds__(256) void k_scan_c2(const int* __restrict__ bexc, int* __restrict__ out,
                                                 int n, int nb) {
    int i = blockIdx.x * 256 + threadIdx.x;
    if (i < n) out[i] += bexc[blockIdx.x];
    if (i == 0) out[n] = bexc[nb];
}

// ---------------- pass B: partition edges into bucket-ordered packed records
__global__ __launch_bounds__(256) void k_partB(const int* __restrict__ EI, const int* __restrict__ flag,
                                               const int* __restrict__ histS, int* __restrict__ edges2,
                                               int E, int N, int K) {
    extern __shared__ int cur[];
    for (int k = threadIdx.x; k < K; k += 256) cur[k] = histS[k * NBLK + blockIdx.x];
    __syncthreads();
    int chunk = (E + NBLK - 1) / NBLK;
    int s = blockIdx.x * chunk, e = min(E, s + chunk);
    bool f = (*flag) != 0;
    for (int i = s + threadIdx.x; i < e; i += 256) {
        int r, c;
        if (f) { const int2* E2 = (const int2*)EI; r = E2[i].x; c = E2[E + i].x; }
        else   { r = EI[i]; c = EI[E + i]; }
        if ((unsigned)r >= (unsigned)N || (unsigned)c >= (unsigned)N) continue;
        int pos = atomicAdd(&cur[c >> 8], 1);
        edges2[pos] = r | ((c & 255) << 20);   // r < 2^20, c_local in bits 20..27
    }
}

// ---------------- per-bucket: fine CSR (deg/start/dinv + edge scatter), all LDS
__global__ __launch_bounds__(256) void k_bucket(const int* __restrict__ histS, const int* __restrict__ edges2,
                                                int* __restrict__ edges, int* __restrict__ start,
                                                float* __restrict__ dinv, int N, int NBtot) {
    __shared__ int hist[256], sd[256], cur[256];
    int b = blockIdx.x, tid = threadIdx.x;
    int base = histS[b * NBLK];
    int end  = histS[(b + 1) * NBLK];
    hist[tid] = 0;
    __syncthreads();
    for (int i = base + tid; i < end; i += 256)
        atomicAdd(&hist[(edges2[i] >> 20) & 255], 1);
    __syncthreads();
    int v = hist[tid];
    sd[tid] = v;
    __syncthreads();
    for (int off = 1; off < 256; off <<= 1) {
        int t = 0;
        if (tid >= off) t = sd[tid - off];
        __syncthreads();
        sd[tid] += t;
        __syncthreads();
    }
    int excl = sd[tid] - v;
    cur[tid] = excl;
    int node = b * 256 + tid;
    if (node < N) {
        start[node] = base + excl;
        dinv[node] = rsqrtf((float)(v + 1));
    }
    if (b == 0 && tid == 0) start[N] = histS[NBtot];
    __syncthreads();
    for (int i = base + tid; i < end; i += 256) {
        int pv = edges2[i];
        int pos = atomicAdd(&cur[(pv >> 20) & 255], 1);
        edges[base + pos] = pv & 0xFFFFF;
    }
}

// W1 [512][64] fp32 -> Wt [64][512] bf16
__global__ __launch_bounds__(256) void k_wt(const float* __restrict__ W, unsigned short* __restrict__ Wt) {
    int i = blockIdx.x * 256 + threadIdx.x;
    int k = i >> 6, n = i & 63;
    Wt[n * 512 + k] = f2bf(W[i]);
}

// ---------------- GEMM1 (MFMA, no LDS): H[m] = dinv[m] * (X[m]·W1), bf16 out
__global__ __launch_bounds__(256) void k_gemm1(const float* __restrict__ X, const unsigned short* __restrict__ Wt,
                                               const float* __restrict__ dinv, unsigned short* __restrict__ H, int N) {
    int tid = threadIdx.x;
    int w = tid >> 6, lane = tid & 63;
    int m_l = lane & 15, q = lane >> 4;
    int m0 = blockIdx.x * 128 + w * 32;
    int rA0 = m0 + m_l, rA1 = m0 + 16 + m_l;
    int rc0 = rA0 < N ? rA0 : N - 1;
    int rc1 = rA1 < N ? rA1 : N - 1;
    const float* baseA0 = X + (size_t)rc0 * 512 + q * 8;
    const float* baseA1 = X + (size_t)rc1 * 512 + q * 8;
    const unsigned short* baseB = Wt + (size_t)m_l * 512 + q * 8;

    f32x4 acc[2][4] = {};
#pragma unroll 4
    for (int c = 0; c < 16; ++c) {
        int ko = c * 32;
        float4 x0a = *(const float4*)(baseA0 + ko);
        float4 x0b = *(const float4*)(baseA0 + ko + 4);
        float4 x1a = *(const float4*)(baseA1 + ko);
        float4 x1b = *(const float4*)(baseA1 + ko + 4);
        bf16x8 a0, a1;
        a0[0] = (short)f2bf(x0a.x); a0[1] = (short)f2bf(x0a.y); a0[2] = (short)f2bf(x0a.z); a0[3] = (short)f2bf(x0a.w);
        a0[4] = (short)f2bf(x0b.x); a0[5] = (short)f2bf(x0b.y); a0[6] = (short)f2bf(x0b.z); a0[7] = (short)f2bf(x0b.w);
        a1[0] = (short)f2bf(x1a.x); a1[1] = (short)f2bf(x1a.y); a1[2] = (short)f2bf(x1a.z); a1[3] = (short)f2bf(x1a.w);
        a1[4] = (short)f2bf(x1b.x); a1[5] = (short)f2bf(x1b.y); a1[6] = (short)f2bf(x1b.z); a1[7] = (short)f2bf(x1b.w);
#pragma unroll
        for (int t = 0; t < 4; ++t) {
            bf16x8 b = *(const bf16x8*)(baseB + (size_t)t * 16 * 512 + ko);
            acc[0][t] = __builtin_amdgcn_mfma_f32_16x16x32_bf16(a0, b, acc[0][t], 0, 0, 0);
            acc[1][t] = __builtin_amdgcn_mfma_f32_16x16x32_bf16(a1, b, acc[1][t], 0, 0, 0);
        }
    }
#pragma unroll
    for (int h = 0; h < 2; ++h) {
#pragma unroll
        for (int rg = 0; rg < 4; ++rg) {
            int row = m0 + h * 16 + q * 4 + rg;
            if (row < N) {
                float dv = dinv[row];
#pragma unroll
                for (int t = 0; t < 4; ++t)
                    H[(size_t)row * 64 + t * 16 + m_l] = f2bf(acc[h][t][rg] * dv);
            }
        }
    }
}

// ---------------- agg1: wave/node, lane=channel, 8 gathers in flight -------
__global__ __launch_bounds__(256) void k_agg1(const unsigned short* __restrict__ H, const int* __restrict__ edges,
                                              const int* __restrict__ start, const float* __restrict__ dinv,
                                              const float* __restrict__ b1, unsigned short* __restrict__ X1, int N) {
    int wid = blockIdx.x * 4 + (threadIdx.x >> 6);
    int lane = threadIdx.x & 63;
    if (wid >= N) return;
    float dv = dinv[wid];
    int s = start[wid], e = start[wid + 1];
    float acc = bf2f(H[(size_t)wid * 64 + lane]);   // self (already dinv-scaled)
    int i = s;
    while (i < e && (i & 3)) { acc += bf2f(H[(size_t)edges[i] * 64 + lane]); ++i; }
    for (; i + 8 <= e; i += 8) {
        int4 e0 = *(const int4*)(edges + i);
        int4 e1 = *(const int4*)(edges + i + 4);
        float h0 = bf2f(H[(size_t)e0.x * 64 + lane]);
        float h1 = bf2f(H[(size_t)e0.y * 64 + lane]);
        float h2 = bf2f(H[(size_t)e0.z * 64 + lane]);
        float h3 = bf2f(H[(size_t)e0.w * 64 + lane]);
        float h4 = bf2f(H[(size_t)e1.x * 64 + lane]);
        float h5 = bf2f(H[(size_t)e1.y * 64 + lane]);
        float h6 = bf2f(H[(size_t)e1.z * 64 + lane]);
        float h7 = bf2f(H[(size_t)e1.w * 64 + lane]);
        acc += ((h0 + h1) + (h2 + h3)) + ((h4 + h5) + (h6 + h7));
    }
    if (i + 4 <= e) {
        int4 e0 = *(const int4*)(edges + i);
        acc += bf2f(H[(size_t)e0.x * 64 + lane]) + bf2f(H[(size_t)e0.y * 64 + lane])
             + bf2f(H[(size_t)e0.z * 64 + lane]) + bf2f(H[(size_t)e0.w * 64 + lane]);
        i += 4;
    }
    for (; i < e; ++i) acc += bf2f(H[(size_t)edges[i] * 64 + lane]);
    float r = acc * dv + b1[lane];
    X1[(size_t)wid * 64 + lane] = f2bf(fmaxf(r, 0.f));
}

// ---------------- GEMM2: bf16 [N,64] x f32 [64,16] -> dinv-scaled bf16 [N,16]
__global__ __launch_bounds__(256) void k_gemm2(const unsigned short* __restrict__ X1, const float* __restrict__ W2,
                                               const float* __restrict__ dinv, unsigned short* __restrict__ H2, int N) {
    __shared__ float Ws[1024];
    __shared__ float Xs[64][68];
    int tid = threadIdx.x;
    for (int i = tid; i < 1024; i += 256) Ws[i] = W2[i];
    int m0 = blockIdx.x * 64;
#pragma unroll
    for (int j = 0; j < 4; ++j) {
        int f = (j * 256 + tid) * 4;
        int r = f >> 6, k = f & 63;
        uint2 v = make_uint2(0u, 0u);
        if (m0 + r < N) v = *(const uint2*)(X1 + (size_t)(m0 + r) * 64 + k);
        Xs[r][k + 0] = bf2f((unsigned short)(v.x & 0xffffu));
        Xs[r][k + 1] = bf2f((unsigned short)(v.x >> 16));
        Xs[r][k + 2] = bf2f((unsigned short)(v.y & 0xffffu));
        Xs[r][k + 3] = bf2f((unsigned short)(v.y >> 16));
    }
    __syncthreads();
    int r = tid >> 2, cq = tid & 3;
    float acc0 = 0.f, acc1 = 0.f, acc2 = 0.f, acc3 = 0.f;
#pragma unroll 8
    for (int k = 0; k < 64; ++k) {
        float xv = Xs[r][k];
        const float* wp = &Ws[k * 16 + cq * 4];
        acc0 += xv * wp[0]; acc1 += xv * wp[1]; acc2 += xv * wp[2]; acc3 += xv * wp[3];
    }
    int m = m0 + r;
    if (m < N) {
        float dv = dinv[m];
        ushort4 o; o.x = f2bf(acc0 * dv); o.y = f2bf(acc1 * dv); o.z = f2bf(acc2 * dv); o.w = f2bf(acc3 * dv);
        *(ushort4*)(H2 + (size_t)m * 16 + cq * 4) = o;
    }
}

// ---------------- agg2: wave/node, 4 edge-slots x 16 ch --------------------
__global__ __launch_bounds__(256) void k_agg2(const unsigned short* __restrict__ H2, const int* __restrict__ edges,
                                              const int* __restrict__ start, const float* __restrict__ dinv,
                                              const float* __restrict__ b2, float* __restrict__ X2, int N) {
    int wid = blockIdx.x * 4 + (threadIdx.x >> 6);
    int lane = threadIdx.x & 63;
    if (wid >= N) return;
    int eo = lane >> 4, c = lane & 15;
    float dv = dinv[wid];
    int s = start[wid], e = start[wid + 1];
    float acc = 0.f;
    int i = s;
    for (; i + 8 <= e; i += 8) {
        int s0 = edges[i + eo], s1 = edges[i + eo + 4];
        acc += bf2f(H2[(size_t)s0 * 16 + c]) + bf2f(H2[(size_t)s1 * 16 + c]);
    }
    for (; i < e; i += 4) {
        int j = i + eo;
        if (j < e) acc += bf2f(H2[(size_t)edges[j] * 16 + c]);
    }
    acc += __shfl_xor(acc, 16, 64);
    acc += __shfl_xor(acc, 32, 64);
    float hs = bf2f(H2[(size_t)wid * 16 + c]);
    float r = (acc + hs) * dv + b2[c];
    if (lane < 16) X2[(size_t)wid * 16 + c] = r;
}

// ---------------- attention head + final linear ----------------
__global__ __launch_bounds__(256) void k_head(const float* __restrict__ X2, const float* __restrict__ G,
                                              const float* __restrict__ AW1, const float* __restrict__ AB1,
                                              const float* __restrict__ AW2, const float* __restrict__ LW,
                                              const float* __restrict__ LB, float* __restrict__ OUT, int N) {
    __shared__ float s_aw1[256], s_ab1[16], s_aw2[16], s_lw[640], s_lb[40];
    int tid = threadIdx.x;
    s_aw1[tid] = AW1[tid];
    if (tid < 16) { s_ab1[tid] = AB1[tid]; s_aw2[tid] = AW2[tid]; }
    for (int i = tid; i < 640; i += 256) s_lw[i] = LW[i];
    if (tid < 40) s_lb[tid] = LB[tid];
    __syncthreads();
    int node = blockIdx.x * 256 + tid;
    if (node >= N) return;
    float x[16], g[16];
    const float4* xp = (const float4*)(X2 + (size_t)node * 16);
    const float4* gp = (const float4*)(G + (size_t)node * 16);
#pragma unroll
    for (int q = 0; q < 4; ++q) {
        float4 v = xp[q]; x[q*4] = v.x; x[q*4+1] = v.y; x[q*4+2] = v.z; x[q*4+3] = v.w;
        float4 u = gp[q]; g[q*4] = u.x; g[q*4+1] = u.y; g[q*4+2] = u.z; g[q*4+3] = u.w;
    }
    float wx = 0.f, wg = 0.f;
#pragma unroll
    for (int j = 0; j < 16; ++j) {
        float tx = s_ab1[j], tg = s_ab1[j];
#pragma unroll
        for (int c = 0; c < 16; ++c) { tx += x[c] * s_aw1[c*16 + j]; tg += g[c] * s_aw1[c*16 + j]; }
        wx += tanhf(tx) * s_aw2[j];
        wg += tanhf(tg) * s_aw2[j];
    }
    float m = fmaxf(wx, wg);
    float ex = expf(wx - m), eg = expf(wg - m);
    float inv = 1.f / (ex + eg);
    float bx = ex * inv, bg = eg * inv;
    float emb[16];
#pragma unroll
    for (int c = 0; c < 16; ++c) emb[c] = bx * x[c] + bg * g[c];
    float* op = OUT + (size_t)node * 40;
    for (int o = 0; o < 40; ++o) {
        float a = s_lb[o];
#pragma unroll
        for (int c = 0; c < 16; ++c) a += emb[c] * s_lw[c*40 + o];
        op[o] = a;
    }
}

extern "C" void kernel_launch(void* const* d_in, const int* in_sizes, int n_in,
                              void* d_out, int out_size, void* d_ws, size_t ws_size,
                              hipStream_t stream) {
    const float* X   = (const float*)d_in[0];
    const int*   EI  = (const int*)d_in[1];
    const float* G   = (const float*)d_in[2];
    const float* W1  = (const float*)d_in[3];
    const float* B1  = (const float*)d_in[4];
    const float* W2  = (const float*)d_in[5];
    const float* B2  = (const float*)d_in[6];
    const float* AW1 = (const float*)d_in[7];
    const float* AB1 = (const float*)d_in[8];
    const float* AW2 = (const float*)d_in[9];
    const float* LW  = (const float*)d_in[10];
    const float* LB  = (const float*)d_in[11];
    float* OUT = (float*)d_out;

    const int N = in_sizes[0] / N_IN;
    const int E = in_sizes[1] / 2;
    const int NB = (N + 255) / 256;
    const int K  = NB;                 // buckets of 256 destination nodes
    const int NH = K * NBLK;           // hist entries
    const int SB = (NH + 255) / 256;   // scan blocks for hist

    char* w = (char*)d_ws;
    size_t off = 0;
    auto take = [&](size_t bytes) -> void* {
        void* p = (void*)(w + off);
        off = (off + bytes + 255) & ~(size_t)255;
        return p;
    };
    int*   flag   = (int*)take(16);
    int*   hist   = (int*)take((size_t)NH * 4);
    int*   histS  = (int*)take((size_t)(NH + 1) * 4);
    int*   bsum   = (int*)take((size_t)SB * 4);
    int*   bexc   = (int*)take((size_t)(SB + 1) * 4);
    int*   startp = (int*)take((size_t)(N + 1) * 4);
    float* dinvp  = (float*)take((size_t)N * 4);
    int*   edges2 = (int*)take((size_t)E * 4);
    int*   edges  = (int*)take((size_t)E * 4);
    unsigned short* wt = (unsigned short*)take((size_t)N_IN * HID * 2);
    unsigned short* h1 = (unsigned short*)take((size_t)N * 64 * 2);
    unsigned short* x1 = (unsigned short*)take((size_t)N * 64 * 2);
    unsigned short* h2 = (unsigned short*)take((size_t)N * 16 * 2);
    float* x2 = (float*)take((size_t)N * 16 * 4);
    (void)ws_size; (void)n_in; (void)out_size;

    k_detect <<<1, 64, 0, stream>>>(EI, flag);
    k_histA  <<<NBLK, 256, K * 4, stream>>>(EI, flag, hist, E, N, K);
    k_scan_a2<<<SB, 256, 0, stream>>>(hist, histS, bsum, NH);
    k_scan_b <<<1, 512, 0, stream>>>(bsum, bexc, SB);
    k_scan_c2<<<SB, 256, 0, stream>>>(bexc, histS, NH, SB);
    k_partB  <<<NBLK, 256, K * 4, stream>>>(EI, flag, histS, edges2, E, N, K);
    k_bucket <<<K, 256, 0, stream>>>(histS, edges2, edges, startp, dinvp, N, NH);
    k_wt     <<<(N_IN * HID + 255) / 256, 256, 0, stream>>>(W1, wt);
    k_gemm1  <<<(N + 127) / 128, 256, 0, stream>>>(X, wt, dinvp, h1, N);
    k_agg1   <<<(N + 3) / 4, 256, 0, stream>>>(h1, edges, startp, dinvp, B1, x1, N);
    k_gemm2  <<<(N + 63) / 64, 256, 0, stream>>>(x1, W2, dinvp, h2, N);
    k_agg2   <<<(N + 3) / 4, 256, 0, stream>>>(h2, edges, startp, dinvp, B2, x2, N);
    k_head   <<<NB, 256, 0, stream>>>(x2, G, AW1, AB1, AW2, LW, LB, OUT, N);
}

// Round 4
// 577.020 us; speedup vs baseline: 1.6113x; 1.0359x over previous
//
#include <hip/hip_runtime.h>

#define N_IN 512
#define HID 64
#define NBLK 256   // edge-chunk blocks for hist/partition passes

typedef __attribute__((ext_vector_type(4))) float f32x4;
typedef __attribute__((ext_vector_type(8))) short bf16x8;

__device__ inline float bf2f(unsigned short s) {
    union { unsigned int u; float f; } v; v.u = ((unsigned int)s) << 16; return v.f;
}
__device__ inline unsigned short f2bf(float f) {
    union { float f; unsigned int u; } v; v.f = f;
    unsigned int u = v.u;
    return (unsigned short)((u + 0x7FFFu + ((u >> 16) & 1u)) >> 16);
}

// ---------------- detect int64-vs-int32 edge storage ----------
__global__ void k_detect(const int* __restrict__ EI, int* __restrict__ flag) {
    if (threadIdx.x == 0 && blockIdx.x == 0)
        *flag = (EI[1] == 0 && EI[3] == 0 && EI[5] == 0 && EI[7] == 0) ? 1 : 0;
}

// ---------------- pass A: per-(bucket, block) histogram (LDS atomics only) --
__global__ __launch_bounds__(256) void k_histA(const int* __restrict__ EI, const int* __restrict__ flag,
                                               int* __restrict__ hist, int E, int N, int K) {
    extern __shared__ int hs[];
    for (int k = threadIdx.x; k < K; k += 256) hs[k] = 0;
    __syncthreads();
    int chunk = (E + NBLK - 1) / NBLK;
    int s = blockIdx.x * chunk, e = min(E, s + chunk);
    bool f = (*flag) != 0;
    for (int i = s + threadIdx.x; i < e; i += 256) {
        int c = f ? ((const int2*)EI)[E + i].x : EI[E + i];
        if ((unsigned)c < (unsigned)N) atomicAdd(&hs[c >> 8], 1);
    }
    __syncthreads();
    for (int k = threadIdx.x; k < K; k += 256) hist[k * NBLK + blockIdx.x] = hs[k];
}

// ---------------- generic 3-phase exclusive scan ----------------
__global__ __launch_bounds__(256) void k_scan_a2(const int* __restrict__ in, int* __restrict__ out,
                                                 int* __restrict__ bsum, int n) {
    __shared__ int sd[256];
    int i = blockIdx.x * 256 + threadIdx.x;
    int v = (i < n) ? in[i] : 0;
    sd[threadIdx.x] = v;
    __syncthreads();
    for (int off = 1; off < 256; off <<= 1) {
        int t = 0;
        if (threadIdx.x >= (unsigned)off) t = sd[threadIdx.x - off];
        __syncthreads();
        sd[threadIdx.x] += t;
        __syncthreads();
    }
    if (i < n) out[i] = sd[threadIdx.x] - v;
    if (threadIdx.x == 255) bsum[blockIdx.x] = sd[255];
}

__global__ __launch_bounds__(512) void k_scan_b(const int* __restrict__ bsum, int* __restrict__ bexc, int nb) {
    __shared__ int sd[512];
    int t = threadIdx.x;
    int v = (t < nb) ? bsum[t] : 0;
    sd[t] = v;
    __syncthreads();
    for (int off = 1; off < 512; off <<= 1) {
        int u = 0;
        if (t >= off) u = sd[t - off];
        __syncthreads();
        sd[t] += u;
        __syncthreads();
    }
    if (t < nb) bexc[t] = sd[t] - v;
    if (t == 511) bexc[nb] = sd[511];
}

__global__ __launch_bounds__(256) void k_scan_c2(const int* __restrict__ bexc, int* __restrict__ out,
                                                 int n, int nb) {
    int i = blockIdx.x * 256 + threadIdx.x;
    if (i < n) out[i] += bexc[blockIdx.x];
    if (i == 0) out[n] = bexc[nb];
}

// ---------------- pass B: partition edges into bucket-ordered packed records
__global__ __launch_bounds__(256) void k_partB(const int* __restrict__ EI, const int* __restrict__ flag,
                                               const int* __restrict__ histS, int* __restrict__ edges2,
                                               int E, int N, int K) {
    extern __shared__ int cur[];
    for (int k = threadIdx.x; k < K; k += 256) cur[k] = histS[k * NBLK + blockIdx.x];
    __syncthreads();
    int chunk = (E + NBLK - 1) / NBLK;
    int s = blockIdx.x * chunk, e = min(E, s + chunk);
    bool f = (*flag) != 0;
    for (int i = s + threadIdx.x; i < e; i += 256) {
        int r, c;
        if (f) { const int2* E2 = (const int2*)EI; r = E2[i].x; c = E2[E + i].x; }
        else   { r = EI[i]; c = EI[E + i]; }
        if ((unsigned)r >= (unsigned)N || (unsigned)c >= (unsigned)N) continue;
        int pos = atomicAdd(&cur[c >> 8], 1);
        edges2[pos] = r | ((c & 255) << 20);   // r < 2^20, c_local in bits 20..27
    }
}

// ---------------- per-bucket: fine CSR (deg/start/dinv + edge scatter), all LDS
__global__ __launch_bounds__(256) void k_bucket(const int* __restrict__ histS, const int* __restrict__ edges2,
                                                int* __restrict__ edges, int* __restrict__ start,
                                                float* __restrict__ dinv, int N, int NBtot) {
    __shared__ int hist[256], sd[256], cur[256];
    int b = blockIdx.x, tid = threadIdx.x;
    int base = histS[b * NBLK];
    int end  = histS[(b + 1) * NBLK];
    hist[tid] = 0;
    __syncthreads();
    for (int i = base + tid; i < end; i += 256)
        atomicAdd(&hist[(edges2[i] >> 20) & 255], 1);
    __syncthreads();
    int v = hist[tid];
    sd[tid] = v;
    __syncthreads();
    for (int off = 1; off < 256; off <<= 1) {
        int t = 0;
        if (tid >= off) t = sd[tid - off];
        __syncthreads();
        sd[tid] += t;
        __syncthreads();
    }
    int excl = sd[tid] - v;
    cur[tid] = excl;
    int node = b * 256 + tid;
    if (node < N) {
        start[node] = base + excl;
        dinv[node] = rsqrtf((float)(v + 1));
    }
    if (b == 0 && tid == 0) start[N] = histS[NBtot];
    __syncthreads();
    for (int i = base + tid; i < end; i += 256) {
        int pv = edges2[i];
        int pos = atomicAdd(&cur[(pv >> 20) & 255], 1);
        edges[base + pos] = pv & 0xFFFFF;
    }
}

// W1 [512][64] fp32 -> Wt [64][512] bf16
__global__ __launch_bounds__(256) void k_wt(const float* __restrict__ W, unsigned short* __restrict__ Wt) {
    int i = blockIdx.x * 256 + threadIdx.x;
    int k = i >> 6, n = i & 63;
    Wt[n * 512 + k] = f2bf(W[i]);
}

// ---------------- GEMM1 (MFMA, no LDS): H[m] = dinv[m] * (X[m]·W1), bf16 out
__global__ __launch_bounds__(256) void k_gemm1(const float* __restrict__ X, const unsigned short* __restrict__ Wt,
                                               const float* __restrict__ dinv, unsigned short* __restrict__ H, int N) {
    int tid = threadIdx.x;
    int w = tid >> 6, lane = tid & 63;
    int m_l = lane & 15, q = lane >> 4;
    int m0 = blockIdx.x * 128 + w * 32;
    int rA0 = m0 + m_l, rA1 = m0 + 16 + m_l;
    int rc0 = rA0 < N ? rA0 : N - 1;
    int rc1 = rA1 < N ? rA1 : N - 1;
    const float* baseA0 = X + (size_t)rc0 * 512 + q * 8;
    const float* baseA1 = X + (size_t)rc1 * 512 + q * 8;
    const unsigned short* baseB = Wt + (size_t)m_l * 512 + q * 8;

    f32x4 acc[2][4] = {};
#pragma unroll 4
    for (int c = 0; c < 16; ++c) {
        int ko = c * 32;
        float4 x0a = *(const float4*)(baseA0 + ko);
        float4 x0b = *(const float4*)(baseA0 + ko + 4);
        float4 x1a = *(const float4*)(baseA1 + ko);
        float4 x1b = *(const float4*)(baseA1 + ko + 4);
        bf16x8 a0, a1;
        a0[0] = (short)f2bf(x0a.x); a0[1] = (short)f2bf(x0a.y); a0[2] = (short)f2bf(x0a.z); a0[3] = (short)f2bf(x0a.w);
        a0[4] = (short)f2bf(x0b.x); a0[5] = (short)f2bf(x0b.y); a0[6] = (short)f2bf(x0b.z); a0[7] = (short)f2bf(x0b.w);
        a1[0] = (short)f2bf(x1a.x); a1[1] = (short)f2bf(x1a.y); a1[2] = (short)f2bf(x1a.z); a1[3] = (short)f2bf(x1a.w);
        a1[4] = (short)f2bf(x1b.x); a1[5] = (short)f2bf(x1b.y); a1[6] = (short)f2bf(x1b.z); a1[7] = (short)f2bf(x1b.w);
#pragma unroll
        for (int t = 0; t < 4; ++t) {
            bf16x8 b = *(const bf16x8*)(baseB + (size_t)t * 16 * 512 + ko);
            acc[0][t] = __builtin_amdgcn_mfma_f32_16x16x32_bf16(a0, b, acc[0][t], 0, 0, 0);
            acc[1][t] = __builtin_amdgcn_mfma_f32_16x16x32_bf16(a1, b, acc[1][t], 0, 0, 0);
        }
    }
#pragma unroll
    for (int h = 0; h < 2; ++h) {
#pragma unroll
        for (int rg = 0; rg < 4; ++rg) {
            int row = m0 + h * 16 + q * 4 + rg;
            if (row < N) {
                float dv = dinv[row];
#pragma unroll
                for (int t = 0; t < 4; ++t)
                    H[(size_t)row * 64 + t * 16 + m_l] = f2bf(acc[h][t][rg] * dv);
            }
        }
    }
}

// ---------------- agg1: wave/node, 16 lanes per edge (8B each), 4 edge slots
__global__ __launch_bounds__(256) void k_agg1(const unsigned short* __restrict__ H, const int* __restrict__ edges,
                                              const int* __restrict__ start, const float* __restrict__ dinv,
                                              const float* __restrict__ b1, unsigned short* __restrict__ X1, int N) {
    int wid = blockIdx.x * 4 + (threadIdx.x >> 6);
    int lane = threadIdx.x & 63;
    if (wid >= N) return;
    int g = lane >> 4;                  // edge slot 0..3
    int c4 = lane & 15;                 // channel group: channels c4*4 .. +3
    const size_t coff = (size_t)c4 * 4; // ushort offset in row
    float a0 = 0.f, a1 = 0.f, a2 = 0.f, a3 = 0.f;
    int s = start[wid], e = start[wid + 1];
    int i = s;
    if ((i & 3) && i < e) {             // peel to 16B-aligned edge index
        int lim = min(e, (i + 3) & ~3);
        int j = i + g;
        if (j < lim) {
            uint2 v = *(const uint2*)(H + (size_t)edges[j] * 64 + coff);
            a0 += __uint_as_float(v.x << 16);
            a1 += __uint_as_float(v.x & 0xffff0000u);
            a2 += __uint_as_float(v.y << 16);
            a3 += __uint_as_float(v.y & 0xffff0000u);
        }
        i = lim;
    }
    for (; i + 16 <= e; i += 16) {      // 16 edges: 1 idx int4 + 4 gathers
        int4 sv = *(const int4*)(edges + i + g * 4);
        uint2 v0 = *(const uint2*)(H + (size_t)sv.x * 64 + coff);
        uint2 v1 = *(const uint2*)(H + (size_t)sv.y * 64 + coff);
        uint2 v2 = *(const uint2*)(H + (size_t)sv.z * 64 + coff);
        uint2 v3 = *(const uint2*)(H + (size_t)sv.w * 64 + coff);
        a0 += __uint_as_float(v0.x << 16) + __uint_as_float(v1.x << 16)
            + __uint_as_float(v2.x << 16) + __uint_as_float(v3.x << 16);
        a1 += __uint_as_float(v0.x & 0xffff0000u) + __uint_as_float(v1.x & 0xffff0000u)
            + __uint_as_float(v2.x & 0xffff0000u) + __uint_as_float(v3.x & 0xffff0000u);
        a2 += __uint_as_float(v0.y << 16) + __uint_as_float(v1.y << 16)
            + __uint_as_float(v2.y << 16) + __uint_as_float(v3.y << 16);
        a3 += __uint_as_float(v0.y & 0xffff0000u) + __uint_as_float(v1.y & 0xffff0000u)
            + __uint_as_float(v2.y & 0xffff0000u) + __uint_as_float(v3.y & 0xffff0000u);
    }
    for (; i < e; i += 4) {             // guarded 4-edge tail
        int j = i + g;
        if (j < e) {
            uint2 v = *(const uint2*)(H + (size_t)edges[j] * 64 + coff);
            a0 += __uint_as_float(v.x << 16);
            a1 += __uint_as_float(v.x & 0xffff0000u);
            a2 += __uint_as_float(v.y << 16);
            a3 += __uint_as_float(v.y & 0xffff0000u);
        }
    }
    a0 += __shfl_xor(a0, 16, 64); a0 += __shfl_xor(a0, 32, 64);
    a1 += __shfl_xor(a1, 16, 64); a1 += __shfl_xor(a1, 32, 64);
    a2 += __shfl_xor(a2, 16, 64); a2 += __shfl_xor(a2, 32, 64);
    a3 += __shfl_xor(a3, 16, 64); a3 += __shfl_xor(a3, 32, 64);
    if (g == 0) {
        float dv = dinv[wid];
        uint2 sv = *(const uint2*)(H + (size_t)wid * 64 + coff);   // self (pre-scaled)
        a0 += __uint_as_float(sv.x << 16);
        a1 += __uint_as_float(sv.x & 0xffff0000u);
        a2 += __uint_as_float(sv.y << 16);
        a3 += __uint_as_float(sv.y & 0xffff0000u);
        float4 bv = *(const float4*)(b1 + c4 * 4);
        ushort4 o;
        o.x = f2bf(fmaxf(a0 * dv + bv.x, 0.f));
        o.y = f2bf(fmaxf(a1 * dv + bv.y, 0.f));
        o.z = f2bf(fmaxf(a2 * dv + bv.z, 0.f));
        o.w = f2bf(fmaxf(a3 * dv + bv.w, 0.f));
        *(ushort4*)(X1 + (size_t)wid * 64 + coff) = o;
    }
}

// ---------------- GEMM2: bf16 [N,64] x f32 [64,16] -> dinv-scaled bf16 [N,16]
__global__ __launch_bounds__(256) void k_gemm2(const unsigned short* __restrict__ X1, const float* __restrict__ W2,
                                               const float* __restrict__ dinv, unsigned short* __restrict__ H2, int N) {
    __shared__ float Ws[1024];
    __shared__ float Xs[64][68];
    int tid = threadIdx.x;
    for (int i = tid; i < 1024; i += 256) Ws[i] = W2[i];
    int m0 = blockIdx.x * 64;
#pragma unroll
    for (int j = 0; j < 4; ++j) {
        int f = (j * 256 + tid) * 4;
        int r = f >> 6, k = f & 63;
        uint2 v = make_uint2(0u, 0u);
        if (m0 + r < N) v = *(const uint2*)(X1 + (size_t)(m0 + r) * 64 + k);
        Xs[r][k + 0] = bf2f((unsigned short)(v.x & 0xffffu));
        Xs[r][k + 1] = bf2f((unsigned short)(v.x >> 16));
        Xs[r][k + 2] = bf2f((unsigned short)(v.y & 0xffffu));
        Xs[r][k + 3] = bf2f((unsigned short)(v.y >> 16));
    }
    __syncthreads();
    int r = tid >> 2, cq = tid & 3;
    float acc0 = 0.f, acc1 = 0.f, acc2 = 0.f, acc3 = 0.f;
#pragma unroll 8
    for (int k = 0; k < 64; ++k) {
        float xv = Xs[r][k];
        const float* wp = &Ws[k * 16 + cq * 4];
        acc0 += xv * wp[0]; acc1 += xv * wp[1]; acc2 += xv * wp[2]; acc3 += xv * wp[3];
    }
    int m = m0 + r;
    if (m < N) {
        float dv = dinv[m];
        ushort4 o; o.x = f2bf(acc0 * dv); o.y = f2bf(acc1 * dv); o.z = f2bf(acc2 * dv); o.w = f2bf(acc3 * dv);
        *(ushort4*)(H2 + (size_t)m * 16 + cq * 4) = o;
    }
}

// ---------------- agg2: wave/node, 8 lanes per edge (4B each), 8 edge slots
__global__ __launch_bounds__(256) void k_agg2(const unsigned short* __restrict__ H2, const int* __restrict__ edges,
                                              const int* __restrict__ start, const float* __restrict__ dinv,
                                              const float* __restrict__ b2, float* __restrict__ X2, int N) {
    int wid = blockIdx.x * 4 + (threadIdx.x >> 6);
    int lane = threadIdx.x & 63;
    if (wid >= N) return;
    int g = lane >> 3;                  // edge slot 0..7
    int c2 = lane & 7;                  // channels 2*c2, 2*c2+1
    const size_t coff = (size_t)c2 * 2;
    float a0 = 0.f, a1 = 0.f;
    int s = start[wid], e = start[wid + 1];
    int i = s;
    if ((i & 3) && i < e) {
        int lim = min(e, (i + 3) & ~3);
        int j = i + g;
        if (j < lim) {
            unsigned int v = *(const unsigned int*)(H2 + (size_t)edges[j] * 16 + coff);
            a0 += __uint_as_float(v << 16);
            a1 += __uint_as_float(v & 0xffff0000u);
        }
        i = lim;
    }
    for (; i + 32 <= e; i += 32) {      // 32 edges: 1 idx int4 + 4 gathers
        int4 sv = *(const int4*)(edges + i + g * 4);
        unsigned int v0 = *(const unsigned int*)(H2 + (size_t)sv.x * 16 + coff);
        unsigned int v1 = *(const unsigned int*)(H2 + (size_t)sv.y * 16 + coff);
        unsigned int v2 = *(const unsigned int*)(H2 + (size_t)sv.z * 16 + coff);
        unsigned int v3 = *(const unsigned int*)(H2 + (size_t)sv.w * 16 + coff);
        a0 += __uint_as_float(v0 << 16) + __uint_as_float(v1 << 16)
            + __uint_as_float(v2 << 16) + __uint_as_float(v3 << 16);
        a1 += __uint_as_float(v0 & 0xffff0000u) + __uint_as_float(v1 & 0xffff0000u)
            + __uint_as_float(v2 & 0xffff0000u) + __uint_as_float(v3 & 0xffff0000u);
    }
    for (; i < e; i += 8) {             // guarded 8-edge tail
        int j = i + g;
        if (j < e) {
            unsigned int v = *(const unsigned int*)(H2 + (size_t)edges[j] * 16 + coff);
            a0 += __uint_as_float(v << 16);
            a1 += __uint_as_float(v & 0xffff0000u);
        }
    }
    a0 += __shfl_xor(a0, 8, 64); a0 += __shfl_xor(a0, 16, 64); a0 += __shfl_xor(a0, 32, 64);
    a1 += __shfl_xor(a1, 8, 64); a1 += __shfl_xor(a1, 16, 64); a1 += __shfl_xor(a1, 32, 64);
    if (g == 0) {
        float dv = dinv[wid];
        unsigned int sv = *(const unsigned int*)(H2 + (size_t)wid * 16 + coff);  // self (pre-scaled)
        a0 += __uint_as_float(sv << 16);
        a1 += __uint_as_float(sv & 0xffff0000u);
        float2 bv = *(const float2*)(b2 + c2 * 2);
        float2 o; o.x = a0 * dv + bv.x; o.y = a1 * dv + bv.y;
        *(float2*)(X2 + (size_t)wid * 16 + coff) = o;
    }
}

// ---------------- attention head + final linear ----------------
__global__ __launch_bounds__(256) void k_head(const float* __restrict__ X2, const float* __restrict__ G,
                                              const float* __restrict__ AW1, const float* __restrict__ AB1,
                                              const float* __restrict__ AW2, const float* __restrict__ LW,
                                              const float* __restrict__ LB, float* __restrict__ OUT, int N) {
    __shared__ float s_aw1[256], s_ab1[16], s_aw2[16], s_lw[640], s_lb[40];
    int tid = threadIdx.x;
    s_aw1[tid] = AW1[tid];
    if (tid < 16) { s_ab1[tid] = AB1[tid]; s_aw2[tid] = AW2[tid]; }
    for (int i = tid; i < 640; i += 256) s_lw[i] = LW[i];
    if (tid < 40) s_lb[tid] = LB[tid];
    __syncthreads();
    int node = blockIdx.x * 256 + tid;
    if (node >= N) return;
    float x[16], g[16];
    const float4* xp = (const float4*)(X2 + (size_t)node * 16);
    const float4* gp = (const float4*)(G + (size_t)node * 16);
#pragma unroll
    for (int q = 0; q < 4; ++q) {
        float4 v = xp[q]; x[q*4] = v.x; x[q*4+1] = v.y; x[q*4+2] = v.z; x[q*4+3] = v.w;
        float4 u = gp[q]; g[q*4] = u.x; g[q*4+1] = u.y; g[q*4+2] = u.z; g[q*4+3] = u.w;
    }
    float wx = 0.f, wg = 0.f;
#pragma unroll
    for (int j = 0; j < 16; ++j) {
        float tx = s_ab1[j], tg = s_ab1[j];
#pragma unroll
        for (int c = 0; c < 16; ++c) { tx += x[c] * s_aw1[c*16 + j]; tg += g[c] * s_aw1[c*16 + j]; }
        wx += tanhf(tx) * s_aw2[j];
        wg += tanhf(tg) * s_aw2[j];
    }
    float m = fmaxf(wx, wg);
    float ex = expf(wx - m), eg = expf(wg - m);
    float inv = 1.f / (ex + eg);
    float bx = ex * inv, bg = eg * inv;
    float emb[16];
#pragma unroll
    for (int c = 0; c < 16; ++c) emb[c] = bx * x[c] + bg * g[c];
    float* op = OUT + (size_t)node * 40;
    for (int o = 0; o < 40; ++o) {
        float a = s_lb[o];
#pragma unroll
        for (int c = 0; c < 16; ++c) a += emb[c] * s_lw[c*40 + o];
        op[o] = a;
    }
}

extern "C" void kernel_launch(void* const* d_in, const int* in_sizes, int n_in,
                              void* d_out, int out_size, void* d_ws, size_t ws_size,
                              hipStream_t stream) {
    const float* X   = (const float*)d_in[0];
    const int*   EI  = (const int*)d_in[1];
    const float* G   = (const float*)d_in[2];
    const float* W1  = (const float*)d_in[3];
    const float* B1  = (const float*)d_in[4];
    const float* W2  = (const float*)d_in[5];
    const float* B2  = (const float*)d_in[6];
    const float* AW1 = (const float*)d_in[7];
    const float* AB1 = (const float*)d_in[8];
    const float* AW2 = (const float*)d_in[9];
    const float* LW  = (const float*)d_in[10];
    const float* LB  = (const float*)d_in[11];
    float* OUT = (float*)d_out;

    const int N = in_sizes[0] / N_IN;
    const int E = in_sizes[1] / 2;
    const int NB = (N + 255) / 256;
    const int K  = NB;                 // buckets of 256 destination nodes
    const int NH = K * NBLK;           // hist entries
    const int SB = (NH + 255) / 256;   // scan blocks for hist

    char* w = (char*)d_ws;
    size_t off = 0;
    auto take = [&](size_t bytes) -> void* {
        void* p = (void*)(w + off);
        off = (off + bytes + 255) & ~(size_t)255;
        return p;
    };
    int*   flag   = (int*)take(16);
    int*   hist   = (int*)take((size_t)NH * 4);
    int*   histS  = (int*)take((size_t)(NH + 1) * 4);
    int*   bsum   = (int*)take((size_t)SB * 4);
    int*   bexc   = (int*)take((size_t)(SB + 1) * 4);
    int*   startp = (int*)take((size_t)(N + 1) * 4);
    float* dinvp  = (float*)take((size_t)N * 4);
    int*   edges2 = (int*)take((size_t)E * 4);
    int*   edges  = (int*)take((size_t)E * 4);
    unsigned short* wt = (unsigned short*)take((size_t)N_IN * HID * 2);
    unsigned short* h1 = (unsigned short*)take((size_t)N * 64 * 2);
    unsigned short* x1 = (unsigned short*)take((size_t)N * 64 * 2);
    unsigned short* h2 = (unsigned short*)take((size_t)N * 16 * 2);
    float* x2 = (float*)take((size_t)N * 16 * 4);
    (void)ws_size; (void)n_in; (void)out_size;

    k_detect <<<1, 64, 0, stream>>>(EI, flag);
    k_histA  <<<NBLK, 256, K * 4, stream>>>(EI, flag, hist, E, N, K);
    k_scan_a2<<<SB, 256, 0, stream>>>(hist, histS, bsum, NH);
    k_scan_b <<<1, 512, 0, stream>>>(bsum, bexc, SB);
    k_scan_c2<<<SB, 256, 0, stream>>>(bexc, histS, NH, SB);
    k_partB  <<<NBLK, 256, K * 4, stream>>>(EI, flag, histS, edges2, E, N, K);
    k_bucket <<<K, 256, 0, stream>>>(histS, edges2, edges, startp, dinvp, N, NH);
    k_wt     <<<(N_IN * HID + 255) / 256, 256, 0, stream>>>(W1, wt);
    k_gemm1  <<<(N + 127) / 128, 256, 0, stream>>>(X, wt, dinvp, h1, N);
    k_agg1   <<<(N + 3) / 4, 256, 0, stream>>>(h1, edges, startp, dinvp, B1, x1, N);
    k_gemm2  <<<(N + 63) / 64, 256, 0, stream>>>(x1, W2, dinvp, h2, N);
    k_agg2   <<<(N + 3) / 4, 256, 0, stream>>>(h2, edges, startp, dinvp, B2, x2, N);
    k_head   <<<NB, 256, 0, stream>>>(x2, G, AW1, AB1, AW2, LW, LB, OUT, N);
}